// Round 2
// baseline (149.025 us; speedup 1.0000x reference)
//
#include <hip/hip_runtime.h>
#include <hip/hip_bf16.h>
#include <math.h>

#define BB 4
#define HH 256
#define LL 1024
#define NN 128
#define NPAIRS 8128  // 128*127/2

// Mask is a 4-byte type on device (int32 0/1 or float32 0.0/1.0).
// Truth test = (bits != 0), valid for both encodings.

// inv_denom[b][n] = 1 / max(sum_{l=1..L-1} mask[b][l][n], 1)
__global__ void count_kernel(const unsigned int* __restrict__ mask,
                             float* __restrict__ inv) {
    int b = blockIdx.x;
    int n = threadIdx.x;
    const unsigned int* mb = mask + (size_t)b * LL * NN;
    int cnt = 0;
    for (int l = 1; l < LL; ++l) cnt += (mb[l * NN + n] != 0u);
    inv[b * NN + n] = 1.0f / (float)max(cnt, 1);
}

// One block per (b,h). meanT[b][n][h] = (1/denom[b][n]) * sum_l mask*in
__global__ __launch_bounds__(256) void mean_kernel(
        const float* __restrict__ in,
        const unsigned int* __restrict__ mask,
        const float* __restrict__ inv,
        float* __restrict__ meanT) {
    int bh = blockIdx.x;
    int b = bh >> 8;          // / HH
    int h = bh & (HH - 1);
    int tid = threadIdx.x;
    int nv = tid & 31;        // n-quad index: covers n = 4*nv .. 4*nv+3
    int g  = tid >> 5;        // l-group 0..7

    const float* base = in + (size_t)bh * LL * NN;
    const unsigned int* mb = mask + (size_t)b * LL * NN;

    float4 acc = make_float4(0.f, 0.f, 0.f, 0.f);
    for (int l = 1 + g; l < LL; l += 8) {
        float4 v = *(const float4*)(base + l * NN + nv * 4);
        uint4  m = *(const uint4*)(mb + l * NN + nv * 4);
        acc.x += (m.x != 0u) ? v.x : 0.0f;
        acc.y += (m.y != 0u) ? v.y : 0.0f;
        acc.z += (m.z != 0u) ? v.z : 0.0f;
        acc.w += (m.w != 0u) ? v.w : 0.0f;
    }

    __shared__ float4 s[8][32];
    s[g][nv] = acc;
    __syncthreads();

    if (g == 0) {
        float4 t = s[0][nv];
        #pragma unroll
        for (int k = 1; k < 8; ++k) {
            float4 u = s[k][nv];
            t.x += u.x; t.y += u.y; t.z += u.z; t.w += u.w;
        }
        int n0 = nv * 4;
        float4 iv = *(const float4*)(inv + b * NN + n0);
        float* mt = meanT + (size_t)b * NN * HH + h;
        mt[(size_t)(n0 + 0) * HH] = t.x * iv.x;
        mt[(size_t)(n0 + 1) * HH] = t.y * iv.y;
        mt[(size_t)(n0 + 2) * HH] = t.z * iv.z;
        mt[(size_t)(n0 + 3) * HH] = t.w * iv.w;
    }
}

// One wave (64 lanes) per pair. 4 pairs per 256-thread block.
__global__ __launch_bounds__(256) void pair_kernel(
        const float* __restrict__ meanT, float* __restrict__ out) {
    int wave = threadIdx.x >> 6;
    int lane = threadIdx.x & 63;
    int idx = blockIdx.x * 4 + wave;           // global pair index over B*NPAIRS
    int b = idx / NPAIRS;
    int p = idx - b * NPAIRS;

    // row i such that i*(i-1)/2 <= p < i*(i+1)/2
    int i = (int)((1.0f + sqrtf(1.0f + 8.0f * (float)p)) * 0.5f);
    while (i * (i - 1) / 2 > p) --i;
    while ((i + 1) * i / 2 <= p) ++i;
    int j = p - i * (i - 1) / 2;

    const float* xi = meanT + ((size_t)b * NN + i) * HH;
    const float* xj = meanT + ((size_t)b * NN + j) * HH;
    float4 a = *(const float4*)(xi + lane * 4);
    float4 c = *(const float4*)(xj + lane * 4);
    float dx = a.x - c.x, dy = a.y - c.y, dz = a.z - c.z, dw = a.w - c.w;
    float s = dx * dx + dy * dy + dz * dz + dw * dw;
    #pragma unroll
    for (int off = 32; off > 0; off >>= 1) s += __shfl_down(s, off);
    if (lane == 0) out[idx] = sqrtf(s + 1e-8f);
}

extern "C" void kernel_launch(void* const* d_in, const int* in_sizes, int n_in,
                              void* d_out, int out_size, void* d_ws, size_t ws_size,
                              hipStream_t stream) {
    const float* in = (const float*)d_in[0];
    const unsigned int* mask = (const unsigned int*)d_in[1];
    float* out = (float*)d_out;

    float* inv = (float*)d_ws;            // BB*NN floats = 2 KB
    float* meanT = inv + BB * NN;         // BB*NN*HH floats = 512 KB

    count_kernel<<<BB, NN, 0, stream>>>(mask, inv);
    mean_kernel<<<BB * HH, 256, 0, stream>>>(in, mask, inv, meanT);
    pair_kernel<<<(BB * NPAIRS) / 4, 256, 0, stream>>>(meanT, out);
}

// Round 3
// 117.786 us; speedup vs baseline: 1.2652x; 1.2652x over previous
//
#include <hip/hip_runtime.h>
#include <hip/hip_bf16.h>
#include <math.h>

#define BB 4
#define HH 256
#define LL 1024
#define NN 128
#define NPAIRS 8128  // 128*127/2

// Pack the 4-byte mask (int32 0/1 or fp32 0.0/1.0; truth = bits!=0) into
// 0/1 bytes so the mean pass moves 4x fewer mask bytes through L1/L2.
__global__ __launch_bounds__(256) void pack_kernel(
        const unsigned int* __restrict__ mask,
        unsigned char* __restrict__ pm) {
    int idx = blockIdx.x * 256 + threadIdx.x;   // handles 4 elements
    uint4 m = *(const uint4*)(mask + (size_t)idx * 4);
    uchar4 o;
    o.x = m.x ? 1 : 0;
    o.y = m.y ? 1 : 0;
    o.z = m.z ? 1 : 0;
    o.w = m.w ? 1 : 0;
    *(uchar4*)(pm + (size_t)idx * 4) = o;
}

// One block per (b,h). Computes masked sum AND mask count over l=1..L-1,
// then meanT[b][n][h] = sum / max(count,1).
__global__ __launch_bounds__(256) void mean_kernel(
        const float* __restrict__ in,
        const unsigned char* __restrict__ pm,
        float* __restrict__ meanT) {
    int bh = blockIdx.x;
    int b = bh >> 8;          // / HH
    int h = bh & (HH - 1);
    int tid = threadIdx.x;
    int nv = tid & 31;        // n-quad index: covers n = 4*nv .. 4*nv+3
    int g  = tid >> 5;        // l-group 0..7

    const float* base = in + (size_t)bh * LL * NN;
    const unsigned char* mb = pm + (size_t)b * LL * NN;

    float4 acc = make_float4(0.f, 0.f, 0.f, 0.f);
    int4 cnt = make_int4(0, 0, 0, 0);
    for (int l = 1 + g; l < LL; l += 8) {
        float4 v = *(const float4*)(base + l * NN + nv * 4);
        uchar4 m = *(const uchar4*)(mb + l * NN + nv * 4);
        acc.x += m.x ? v.x : 0.0f;  cnt.x += m.x;
        acc.y += m.y ? v.y : 0.0f;  cnt.y += m.y;
        acc.z += m.z ? v.z : 0.0f;  cnt.z += m.z;
        acc.w += m.w ? v.w : 0.0f;  cnt.w += m.w;
    }

    __shared__ float4 s[8][32];
    __shared__ int4 c[8][32];
    s[g][nv] = acc;
    c[g][nv] = cnt;
    __syncthreads();

    if (g == 0) {
        float4 t = s[0][nv];
        int4 q = c[0][nv];
        #pragma unroll
        for (int k = 1; k < 8; ++k) {
            float4 u = s[k][nv];
            int4 w = c[k][nv];
            t.x += u.x; t.y += u.y; t.z += u.z; t.w += u.w;
            q.x += w.x; q.y += w.y; q.z += w.z; q.w += w.w;
        }
        int n0 = nv * 4;
        float* mt = meanT + (size_t)b * NN * HH + h;
        mt[(size_t)(n0 + 0) * HH] = t.x / (float)max(q.x, 1);
        mt[(size_t)(n0 + 1) * HH] = t.y / (float)max(q.y, 1);
        mt[(size_t)(n0 + 2) * HH] = t.z / (float)max(q.z, 1);
        mt[(size_t)(n0 + 3) * HH] = t.w / (float)max(q.w, 1);
    }
}

// One wave (64 lanes) per pair. 4 pairs per 256-thread block.
__global__ __launch_bounds__(256) void pair_kernel(
        const float* __restrict__ meanT, float* __restrict__ out) {
    int wave = threadIdx.x >> 6;
    int lane = threadIdx.x & 63;
    int idx = blockIdx.x * 4 + wave;           // global pair index over B*NPAIRS
    int b = idx / NPAIRS;
    int p = idx - b * NPAIRS;

    // row i such that i*(i-1)/2 <= p < i*(i+1)/2
    int i = (int)((1.0f + sqrtf(1.0f + 8.0f * (float)p)) * 0.5f);
    while (i * (i - 1) / 2 > p) --i;
    while ((i + 1) * i / 2 <= p) ++i;
    int j = p - i * (i - 1) / 2;

    const float* xi = meanT + ((size_t)b * NN + i) * HH;
    const float* xj = meanT + ((size_t)b * NN + j) * HH;
    float4 a = *(const float4*)(xi + lane * 4);
    float4 cc = *(const float4*)(xj + lane * 4);
    float dx = a.x - cc.x, dy = a.y - cc.y, dz = a.z - cc.z, dw = a.w - cc.w;
    float s = dx * dx + dy * dy + dz * dz + dw * dw;
    #pragma unroll
    for (int off = 32; off > 0; off >>= 1) s += __shfl_down(s, off);
    if (lane == 0) out[idx] = sqrtf(s + 1e-8f);
}

extern "C" void kernel_launch(void* const* d_in, const int* in_sizes, int n_in,
                              void* d_out, int out_size, void* d_ws, size_t ws_size,
                              hipStream_t stream) {
    const float* in = (const float*)d_in[0];
    const unsigned int* mask = (const unsigned int*)d_in[1];
    float* out = (float*)d_out;

    float* meanT = (float*)d_ws;                     // BB*NN*HH floats = 512 KB
    unsigned char* pm = (unsigned char*)(meanT + BB * NN * HH);  // 512 KB

    pack_kernel<<<(BB * LL * NN) / (256 * 4), 256, 0, stream>>>(mask, pm);
    mean_kernel<<<BB * HH, 256, 0, stream>>>(in, pm, meanT);
    pair_kernel<<<(BB * NPAIRS) / 4, 256, 0, stream>>>(meanT, out);
}

// Round 5
// 96.811 us; speedup vs baseline: 1.5393x; 1.2167x over previous
//
#include <hip/hip_runtime.h>
#include <hip/hip_bf16.h>
#include <math.h>

#define BB 4
#define HH 256
#define LL 1024
#define NN 128
#define NPAIRS 8128  // 128*127/2

typedef float f32x4 __attribute__((ext_vector_type(4)));

// Pack the 4-byte mask (truth = bits!=0) into 0/1 bytes: 4x less mask
// traffic downstream, and 512KB/b stays L2-resident under the input stream.
__global__ __launch_bounds__(256) void pack_kernel(
        const unsigned int* __restrict__ mask,
        unsigned char* __restrict__ pm) {
    int idx = blockIdx.x * 256 + threadIdx.x;   // handles 4 elements
    uint4 m = *(const uint4*)(mask + (size_t)idx * 4);
    uchar4 o;
    o.x = m.x ? 1 : 0;
    o.y = m.y ? 1 : 0;
    o.z = m.z ? 1 : 0;
    o.w = m.w ? 1 : 0;
    *(uchar4*)(pm + (size_t)idx * 4) = o;
}

// One block of 512 threads per (b,h): 32 waves/CU at 4 blocks/CU.
// Masked sum + count over l=1..L-1, then meanT[b][n][h] = sum/max(count,1).
// Input loads are nontemporal: the 537MB stream is touched once and must
// not evict the packed mask from L2.
__global__ __launch_bounds__(512) void mean_kernel(
        const float* __restrict__ in,
        const unsigned char* __restrict__ pm,
        float* __restrict__ meanT) {
    int bh = blockIdx.x;
    int b = bh >> 8;          // / HH
    int h = bh & (HH - 1);
    int tid = threadIdx.x;
    int nv = tid & 31;        // n-quad index: covers n = 4*nv .. 4*nv+3
    int g  = tid >> 5;        // l-group 0..15

    const float* base = in + (size_t)bh * LL * NN;
    const unsigned char* mb = pm + (size_t)b * LL * NN;

    float4 acc = make_float4(0.f, 0.f, 0.f, 0.f);
    int4 cnt = make_int4(0, 0, 0, 0);
    #pragma unroll 4
    for (int l = 1 + g; l < LL; l += 16) {
        f32x4 v = __builtin_nontemporal_load((const f32x4*)(base + l * NN + nv * 4));
        uchar4 m = *(const uchar4*)(mb + l * NN + nv * 4);
        acc.x += m.x ? v.x : 0.0f;  cnt.x += m.x;
        acc.y += m.y ? v.y : 0.0f;  cnt.y += m.y;
        acc.z += m.z ? v.z : 0.0f;  cnt.z += m.z;
        acc.w += m.w ? v.w : 0.0f;  cnt.w += m.w;
    }

    __shared__ float4 s[16][32];
    __shared__ int4 c[16][32];
    s[g][nv] = acc;
    c[g][nv] = cnt;
    __syncthreads();

    if (g == 0) {
        float4 t = s[0][nv];
        int4 q = c[0][nv];
        #pragma unroll
        for (int k = 1; k < 16; ++k) {
            float4 u = s[k][nv];
            int4 w = c[k][nv];
            t.x += u.x; t.y += u.y; t.z += u.z; t.w += u.w;
            q.x += w.x; q.y += w.y; q.z += w.z; q.w += w.w;
        }
        int n0 = nv * 4;
        float* mt = meanT + (size_t)b * NN * HH + h;
        mt[(size_t)(n0 + 0) * HH] = t.x / (float)max(q.x, 1);
        mt[(size_t)(n0 + 1) * HH] = t.y / (float)max(q.y, 1);
        mt[(size_t)(n0 + 2) * HH] = t.z / (float)max(q.z, 1);
        mt[(size_t)(n0 + 3) * HH] = t.w / (float)max(q.w, 1);
    }
}

// One wave (64 lanes) per pair. 4 pairs per 256-thread block.
__global__ __launch_bounds__(256) void pair_kernel(
        const float* __restrict__ meanT, float* __restrict__ out) {
    int wave = threadIdx.x >> 6;
    int lane = threadIdx.x & 63;
    int idx = blockIdx.x * 4 + wave;           // global pair index over B*NPAIRS
    int b = idx / NPAIRS;
    int p = idx - b * NPAIRS;

    // row i such that i*(i-1)/2 <= p < i*(i+1)/2
    int i = (int)((1.0f + sqrtf(1.0f + 8.0f * (float)p)) * 0.5f);
    while (i * (i - 1) / 2 > p) --i;
    while ((i + 1) * i / 2 <= p) ++i;
    int j = p - i * (i - 1) / 2;

    const float* xi = meanT + ((size_t)b * NN + i) * HH;
    const float* xj = meanT + ((size_t)b * NN + j) * HH;
    float4 a = *(const float4*)(xi + lane * 4);
    float4 cc = *(const float4*)(xj + lane * 4);
    float dx = a.x - cc.x, dy = a.y - cc.y, dz = a.z - cc.z, dw = a.w - cc.w;
    float s = dx * dx + dy * dy + dz * dz + dw * dw;
    #pragma unroll
    for (int off = 32; off > 0; off >>= 1) s += __shfl_down(s, off);
    if (lane == 0) out[idx] = sqrtf(s + 1e-8f);
}

extern "C" void kernel_launch(void* const* d_in, const int* in_sizes, int n_in,
                              void* d_out, int out_size, void* d_ws, size_t ws_size,
                              hipStream_t stream) {
    const float* in = (const float*)d_in[0];
    const unsigned int* mask = (const unsigned int*)d_in[1];
    float* out = (float*)d_out;

    float* meanT = (float*)d_ws;                     // BB*NN*HH floats = 512 KB
    unsigned char* pm = (unsigned char*)(meanT + BB * NN * HH);  // 512 KB

    pack_kernel<<<(BB * LL * NN) / (256 * 4), 256, 0, stream>>>(mask, pm);
    mean_kernel<<<BB * HH, 512, 0, stream>>>(in, pm, meanT);
    pair_kernel<<<(BB * NPAIRS) / 4, 256, 0, stream>>>(meanT, out);
}